// Round 2
// baseline (1284.488 us; speedup 1.0000x reference)
//
#include <hip/hip_runtime.h>
#include <hip/hip_cooperative_groups.h>

namespace cg = cooperative_groups;

#define SCAN_BS 256
#define SCAN_IT 16
#define SCAN_CHUNK (SCAN_BS * SCAN_IT)   // 4096 words per chunk
#define NVOX 10000000
#define NAVOX 5000000
#define NWORDS1 312500                   // ceil(NVOX/32)
#define NWORDS2 156250                   // ceil(NAVOX/32)
#define VXYZK 1250000
#define BLK1 ((NWORDS1 + SCAN_CHUNK - 1) / SCAN_CHUNK)   // 77
#define BLK2 ((NWORDS2 + SCAN_CHUNK - 1) / SCAN_CHUNK)   // 39

struct Params {
  const float* pf; const float* pc; const int* bidx; const void* fgp;
  const float* Wpf; const float* bpf; const float* gpf; const float* bepf;
  const float* mpf; const float* vpf;
  const float* Wcp; const float* bcp; const float* gcp; const float* becp;
  const float* mcp; const float* vcp;
  float* out;
  unsigned* bits; unsigned* abits; float* cnt; float* acnt;
  unsigned* flag; unsigned* gcnt; unsigned char* needp; int* ctr;
  unsigned* wordpfx; unsigned* awordpfx; unsigned* bsums1; unsigned* bsums2;
  int* vkey;   // reused as mlist after P3
  int* inv; int* ukey;
  int* akey;   // reused as plist after P6
  int* ainv_u; int* nlist; int* clist;
  float* csum; float* asum;
  uint4* zbase; int zwords;   // 16B units to zero
  int N;
};

__device__ __forceinline__ float leakyf(float x) { return x >= 0.0f ? x : 0.1f * x; }

__device__ __forceinline__ int fg_get(const void* fgp, int i, int mode) {
  return mode ? (((const unsigned char*)fgp)[i] != 0) : (((const int*)fgp)[i] != 0);
}

__device__ __forceinline__ int rank_of(int key, const unsigned* bits,
                                       const unsigned* wordpfx, const unsigned* bsums) {
  int w = key >> 5, b = key & 31;
  return (int)(wordpfx[w] + bsums[w >> 12] + (unsigned)__popc(bits[w] & ((1u << b) - 1u)));
}

struct ProjSM { float tile[16][128]; int srow[16]; };
struct GemSM  { float tile[16][384]; int si[16]; int sr[16]; int sg[16]; float smc[16]; };
union SM { unsigned scan[SCAN_BS]; ProjSM proj; GemSM gem; };

// per-chunk popcount scan; chunk index = blockIdx.x (caller guards bid < nchunks)
__device__ void scan_pop_phase(const unsigned* __restrict__ bits, int nwords,
                               unsigned* __restrict__ wordpfx, unsigned* __restrict__ bsums,
                               unsigned* s) {
  int tid = threadIdx.x;
  long base = (long)blockIdx.x * SCAN_CHUNK + (long)tid * SCAN_IT;
  unsigned v[SCAN_IT];
  unsigned tsum = 0;
#pragma unroll
  for (int j = 0; j < SCAN_IT; ++j) {
    long idx = base + j;
    v[j] = (idx < (long)nwords) ? (unsigned)__popc(bits[idx]) : 0u;
    tsum += v[j];
  }
  unsigned x = tsum;
  s[tid] = x;
  for (int off = 1; off < SCAN_BS; off <<= 1) {
    __syncthreads();
    unsigned y = (tid >= off) ? s[tid - off] : 0u;
    __syncthreads();
    x += y;
    s[tid] = x;
  }
  if (tid == SCAN_BS - 1) bsums[blockIdx.x] = x;
  unsigned run = x - tsum;
#pragma unroll
  for (int j = 0; j < SCAN_IT; ++j) {
    long idx = base + j;
    if (idx < (long)nwords) { wordpfx[idx] = run; run += v[j]; }
  }
}

// exclusive-scan of chunk sums (n <= 4096), executed by one block
__device__ void scan_sums_phase(unsigned* __restrict__ data, int n, int* totalOut, unsigned* s) {
  int tid = threadIdx.x;
  int base = tid * SCAN_IT;
  unsigned v[SCAN_IT];
  unsigned tsum = 0;
#pragma unroll
  for (int j = 0; j < SCAN_IT; ++j) {
    int idx = base + j;
    v[j] = (idx < n) ? data[idx] : 0u;
    tsum += v[j];
  }
  unsigned x = tsum;
  s[tid] = x;
  for (int off = 1; off < SCAN_BS; off <<= 1) {
    __syncthreads();
    unsigned y = (tid >= off) ? s[tid - off] : 0u;
    __syncthreads();
    x += y;
    s[tid] = x;
  }
  if (tid == SCAN_BS - 1) *totalOut = (int)x;
  unsigned run = x - tsum;
#pragma unroll
  for (int j = 0; j < SCAN_IT; ++j) {
    int idx = base + j;
    if (idx < n) { data[idx] = run; run += v[j]; }
  }
}

__global__ void k_fused(Params p) {
  cg::grid_group grid = cg::this_grid();
  __shared__ __align__(16) SM sm;
  const int tid = threadIdx.x;
  const int bid = blockIdx.x;
  const int nth = gridDim.x * blockDim.x;
  const int gtid = bid * blockDim.x + tid;
  const int N = p.N;
  volatile int* cv = p.ctr;

  // ---- P0: zero workspace region (replaces memset node) ----
  {
    uint4 z = make_uint4(0u, 0u, 0u, 0u);
    for (int w = gtid; w < p.zwords; w += nth) p.zbase[w] = z;
  }
  grid.sync();

  // ---- P1: passthrough copy out=pf (unroll-4 MLP)  +  voxelize/bits/mode ----
  {
    const int nw = N / 4;
    const unsigned* fgw = (const unsigned*)p.fgp;
    for (int i = gtid; i < N; i += nth) {
      if (i < nw && fgw[i] > 1u) atomicOr(&p.ctr[4], 1);
      float x = p.pc[3 * i], y = p.pc[3 * i + 1], z = p.pc[3 * i + 2];
      int xi = (int)floorf((x - (-50.0f)) / 0.4f);
      int yi = (int)floorf((y - (-50.0f)) / 0.4f);
      int zi = (int)floorf((z - (-5.0f)) / 0.4f);
      xi = min(max(xi, 0), 249); yi = min(max(yi, 0), 249); zi = min(max(zi, 0), 19);
      int b = min(max(p.bidx[i], 0), 7);
      int key = ((b * 250 + xi) * 250 + yi) * 20 + zi;
      p.vkey[i] = key;
      atomicOr(&p.bits[key >> 5], 1u << (key & 31));
    }
    const float4* s4 = (const float4*)p.pf;
    float4* d4 = (float4*)p.out;
    int n4 = N * 32;
    int e = gtid;
    for (; e + 3 * nth < n4; e += 4 * nth) {
      float4 v0 = s4[e], v1 = s4[e + nth], v2 = s4[e + 2 * nth], v3 = s4[e + 3 * nth];
      d4[e] = v0; d4[e + nth] = v1; d4[e + 2 * nth] = v2; d4[e + 3 * nth] = v3;
    }
    for (; e < n4; e += nth) d4[e] = s4[e];
  }
  grid.sync();

  // ---- P2: scan voxel presence bits -> ranks; U -> ctr[0] ----
  if (bid < BLK1) scan_pop_phase(p.bits, NWORDS1, p.wordpfx, p.bsums1, sm.scan);
  grid.sync();
  if (bid == 0) scan_sums_phase(p.bsums1, BLK1, &p.ctr[0], sm.scan);
  grid.sync();

  // ---- P3: inv + ukey + wave-reduced K ----
  {
    int mode = cv[4];
    int iters = (N + nth - 1) / nth;
    for (int it = 0; it < iters; ++it) {
      int i = it * nth + gtid;
      bool valid = i < N;
      int r = 0;
      if (valid) {
        int k = p.vkey[i];
        r = rank_of(k, p.bits, p.wordpfx, p.bsums1);
        p.inv[i] = r;
        p.ukey[r] = k;
      }
      int fgr = (valid && fg_get(p.fgp, i, mode)) ? r : -1;
      for (int off = 32; off > 0; off >>= 1) fgr = max(fgr, __shfl_down(fgr, off));
      if ((tid & 63) == 0 && fgr >= 0) atomicMax(&p.ctr[2], fgr + 1);
    }
  }
  grid.sync();

  // ---- P4: associate keys + presence bits ----
  {
    int U = cv[0];
    for (int r = gtid; r < U; r += nth) {
      int uk = p.ukey[r];
      int ak = (uk / VXYZK / 2) * VXYZK + uk % VXYZK;
      p.akey[r] = ak;
      atomicOr(&p.abits[ak >> 5], 1u << (ak & 31));
    }
  }
  grid.sync();

  // ---- P5: scan associate bits; A -> ctr[1] ----
  if (bid < BLK2) scan_pop_phase(p.abits, NWORDS2, p.awordpfx, p.bsums2, sm.scan);
  grid.sync();
  if (bid == 0) scan_sums_phase(p.bsums2, BLK2, &p.ctr[1], sm.scan);
  grid.sync();

  // ---- P6: ainv + group member count ----
  {
    int U = cv[0];
    for (int r = gtid; r < U; r += nth) {
      int g = rank_of(p.akey[r], p.abits, p.awordpfx, p.bsums2);
      p.ainv_u[r] = g;
      atomicAdd(&p.gcnt[g], 1u);
    }
  }
  grid.sync();

  // ---- P7: build mlist (multi-member) / nlist (valid subset) ----
  {
    int U = cv[0];
    int K = cv[2];
    for (int r = gtid; r < U; r += nth) {
      if (p.gcnt[p.ainv_u[r]] >= 2u) {
        int mp = atomicAdd(&p.ctr[5], 1);
        p.vkey[mp] = r;                 // mlist aliases vkey (dead after P3)
        if (r < K) {
          p.needp[r] = 1;
          int np = atomicAdd(&p.ctr[6], 1);
          p.nlist[np] = r;
        }
      }
    }
  }
  grid.sync();

  // ---- P8: zero needed csum/asum rows + filter contributing fg points ----
  {
    int K = cv[2];
    int mcount = cv[5];
    int mode = cv[4];
    int totalA = mcount * 128;
    for (int idx = gtid; idx < totalA; idx += nth) {
      int r = p.vkey[idx >> 7];        // mlist
      int d = idx & 127;
      p.asum[(size_t)p.ainv_u[r] * 128 + d] = 0.0f;
      if (r < K) p.csum[(size_t)r * 128 + d] = 0.0f;
    }
    for (int i = gtid; i < N; i += nth) {
      if (!fg_get(p.fgp, i, mode)) continue;
      int r = p.inv[i];
      if (!p.needp[r]) continue;
      atomicAdd(&p.cnt[r], 1.0f);
      int q = atomicAdd(&p.ctr[7], 1);
      p.clist[q] = i;
    }
  }
  grid.sync();

  // ---- P9: csum accumulate ----
  {
    int total = cv[7] * 128;
    for (int idx = gtid; idx < total; idx += nth) {
      int i = p.clist[idx >> 7];
      int d = idx & 127;
      atomicAdd(&p.csum[(size_t)p.inv[i] * 128 + d], p.pf[(size_t)i * 128 + d]);
    }
  }
  grid.sync();

  // ---- P10: in-place cluster projection (csum row -> cfa row) ----
  {
    int nc = cv[6];
    int ntiles = (nc + 15) >> 4;
    int d = tid & 127, h = tid >> 7;
    for (int tb = bid; tb < ntiles; tb += gridDim.x) {
      int base = tb * 16;
      if (tid < 16) sm.proj.srow[tid] = (base + tid < nc) ? p.nlist[base + tid] : -1;
      __syncthreads();
      for (int q = h; q < 16; q += 2) {
        int r = sm.proj.srow[q];
        sm.proj.tile[q][d] = (r >= 0) ? p.csum[(size_t)r * 128 + d] / fmaxf(p.cnt[r], 1.0f) : 0.0f;
      }
      __syncthreads();
      float acc[8];
#pragma unroll
      for (int q = 0; q < 8; ++q) acc[q] = 0.0f;
      for (int k4 = 0; k4 < 32; ++k4) {
        float w0 = p.Wcp[(4 * k4 + 0) * 128 + d];
        float w1 = p.Wcp[(4 * k4 + 1) * 128 + d];
        float w2 = p.Wcp[(4 * k4 + 2) * 128 + d];
        float w3 = p.Wcp[(4 * k4 + 3) * 128 + d];
#pragma unroll
        for (int q = 0; q < 8; ++q) {
          float4 t4 = *(const float4*)&sm.proj.tile[h * 8 + q][4 * k4];
          acc[q] = fmaf(t4.x, w0, acc[q]);
          acc[q] = fmaf(t4.y, w1, acc[q]);
          acc[q] = fmaf(t4.z, w2, acc[q]);
          acc[q] = fmaf(t4.w, w3, acc[q]);
        }
      }
      float biasd = p.bcp[d], scale = p.gcp[d] / sqrtf(p.vcp[d] + 1e-5f);
      float md = p.mcp[d], bed = p.becp[d];
      for (int q = 0; q < 8; ++q) {
        int r = sm.proj.srow[h * 8 + q];
        if (r >= 0) {
          float pre = acc[q] + biasd;
          p.csum[(size_t)r * 128 + d] = leakyf((pre - md) * scale + bed);
        }
      }
      __syncthreads();
    }
  }
  grid.sync();

  // ---- P11: asum accumulate over associate groups ----
  {
    int total = cv[6] * 128;
    for (int idx = gtid; idx < total; idx += nth) {
      int r = p.nlist[idx >> 7];
      int d = idx & 127;
      int g = p.ainv_u[r];
      atomicAdd(&p.asum[(size_t)g * 128 + d], p.csum[(size_t)r * 128 + d]);
      if (d == 0) atomicAdd(&p.acnt[g], 1.0f);
    }
  }
  grid.sync();

  // ---- P12: amask flags (per-element diff first; bit-exact singleton cancel) ----
  {
    int mcount = cv[5];
    int K = cv[2];
    int groups = gridDim.x * (blockDim.x >> 6);
    int j0 = bid * (blockDim.x >> 6) + (tid >> 6);
    int lane = tid & 63;
    for (int j = j0; j < mcount; j += groups) {
      int r = p.vkey[j];               // mlist
      int g = p.ainv_u[r];
      float mc = fmaxf(p.acnt[g], 1.0f);
      bool valid = r < K;
      size_t rb = (size_t)r * 128, gb = (size_t)g * 128;
      float c0 = valid ? p.csum[rb + lane] : 0.0f;
      float c1 = valid ? p.csum[rb + 64 + lane] : 0.0f;
      float s = (c0 - p.asum[gb + lane] / mc) + (c1 - p.asum[gb + 64 + lane] / mc);
      for (int off = 32; off > 0; off >>= 1) s += __shfl_down(s, off);
      if (lane == 0) p.flag[r] = (s > 0.0f) ? 1u : 0u;
    }
  }
  grid.sync();

  // ---- P13: flagged-point list (wave-aggregated atomic) ----
  {
    int iters = (N + nth - 1) / nth;
    int lane = tid & 63;
    for (int it = 0; it < iters; ++it) {
      int i = it * nth + gtid;
      bool pred = (i < N) && (p.flag[p.inv[i]] != 0u);
      unsigned long long m = __ballot(pred);
      int cnt = __popcll(m);
      int base = 0;
      if (lane == 0 && cnt) base = atomicAdd(&p.ctr[3], cnt);
      base = __shfl(base, 0);
      if (pred) p.akey[base + __popcll(m & ((1ull << lane) - 1ull))] = i;  // plist
    }
  }
  grid.sync();

  // ---- P14: final GEMM for flagged points only ----
  {
    int pcnt = cv[3];
    if (pcnt > 1) {                     // gate: amask.sum() <= 1 -> pure passthrough
      int K = cv[2];
      int ntiles = (pcnt + 15) >> 4;
      int d = tid & 127, h = tid >> 7;
      for (int tb = bid; tb < ntiles; tb += gridDim.x) {
        int base = tb * 16;
        if (tid < 16) {
          int i = (base + tid < pcnt) ? p.akey[base + tid] : -1;  // plist
          sm.gem.si[tid] = i;
          int r = (i >= 0) ? p.inv[i] : 0;
          sm.gem.sr[tid] = r;
          int g = p.ainv_u[r];
          sm.gem.sg[tid] = g;
          sm.gem.smc[tid] = fmaxf(p.acnt[g], 1.0f);
        }
        __syncthreads();
        for (int e = tid; e < 16 * 96; e += 256) {
          int q = e / 96, f4 = e % 96;
          int i = sm.gem.si[q];
          float4 v = make_float4(0.f, 0.f, 0.f, 0.f);
          if (i >= 0) {
            if (f4 < 32) {
              v = ((const float4*)p.pf)[(size_t)i * 32 + f4];
            } else if (f4 < 64) {
              int r = sm.gem.sr[q];
              if (r < K) v = ((const float4*)p.csum)[(size_t)r * 32 + (f4 - 32)];
            } else {
              float4 a = ((const float4*)p.asum)[(size_t)sm.gem.sg[q] * 32 + (f4 - 64)];
              float mc = sm.gem.smc[q];
              v = make_float4(a.x / mc, a.y / mc, a.z / mc, a.w / mc);
            }
          }
          *(float4*)&sm.gem.tile[q][f4 * 4] = v;
        }
        __syncthreads();
        float acc[8];
#pragma unroll
        for (int q = 0; q < 8; ++q) acc[q] = 0.0f;
        for (int k4 = 0; k4 < 96; ++k4) {
          float w0 = p.Wpf[(4 * k4 + 0) * 128 + d];
          float w1 = p.Wpf[(4 * k4 + 1) * 128 + d];
          float w2 = p.Wpf[(4 * k4 + 2) * 128 + d];
          float w3 = p.Wpf[(4 * k4 + 3) * 128 + d];
#pragma unroll
          for (int q = 0; q < 8; ++q) {
            float4 t4 = *(const float4*)&sm.gem.tile[h * 8 + q][4 * k4];
            acc[q] = fmaf(t4.x, w0, acc[q]);
            acc[q] = fmaf(t4.y, w1, acc[q]);
            acc[q] = fmaf(t4.z, w2, acc[q]);
            acc[q] = fmaf(t4.w, w3, acc[q]);
          }
        }
        float biasd = p.bpf[d], scale = p.gpf[d] / sqrtf(p.vpf[d] + 1e-5f);
        float md = p.mpf[d], bed = p.bepf[d];
        for (int q = 0; q < 8; ++q) {
          int i = sm.gem.si[h * 8 + q];
          if (i >= 0) {
            float pre = acc[q] + biasd;
            p.out[(size_t)i * 128 + d] = leakyf((pre - md) * scale + bed);
          }
        }
        __syncthreads();
      }
    }
  }
}

extern "C" void kernel_launch(void* const* d_in, const int* in_sizes, int n_in,
                              void* d_out, int out_size, void* d_ws, size_t ws_size,
                              hipStream_t stream) {
  (void)n_in; (void)out_size; (void)ws_size;
  Params prm;
  prm.pf   = (const float*)d_in[0];
  prm.pc   = (const float*)d_in[1];
  prm.bidx = (const int*)d_in[2];
  prm.fgp  = d_in[3];
  prm.Wpf  = (const float*)d_in[5];
  prm.bpf  = (const float*)d_in[6];
  prm.gpf  = (const float*)d_in[7];
  prm.bepf = (const float*)d_in[8];
  prm.mpf  = (const float*)d_in[9];
  prm.vpf  = (const float*)d_in[10];
  prm.Wcp  = (const float*)d_in[11];
  prm.bcp  = (const float*)d_in[12];
  prm.gcp  = (const float*)d_in[13];
  prm.becp = (const float*)d_in[14];
  prm.mcp  = (const float*)d_in[15];
  prm.vcp  = (const float*)d_in[16];
  prm.out  = (float*)d_out;
  int N = in_sizes[0] / 128;
  prm.N = N;

  char* ws = (char*)d_ws;
  size_t o = 0;
  auto take = [&](size_t bytes) -> void* {
    void* p = ws + o;
    o += (bytes + 255) & ~(size_t)255;
    return p;
  };
  // ---- zeroed region (zeroed in P0) ----
  prm.bits  = (unsigned*)take((size_t)NWORDS1 * 4);
  prm.abits = (unsigned*)take((size_t)NWORDS2 * 4);
  prm.cnt   = (float*)take((size_t)N * 4);
  prm.acnt  = (float*)take((size_t)N * 4);
  prm.flag  = (unsigned*)take((size_t)N * 4);
  prm.gcnt  = (unsigned*)take((size_t)N * 4);
  prm.needp = (unsigned char*)take((size_t)N);
  prm.ctr   = (int*)take(256);
  size_t zeroBytes = o;
  // ---- scratch (no init needed) ----
  prm.wordpfx  = (unsigned*)take((size_t)NWORDS1 * 4);
  prm.awordpfx = (unsigned*)take((size_t)NWORDS2 * 4);
  prm.bsums1   = (unsigned*)take((size_t)4096 * 4);
  prm.bsums2   = (unsigned*)take((size_t)4096 * 4);
  prm.vkey     = (int*)take((size_t)N * 4);   // reused as mlist
  prm.inv      = (int*)take((size_t)N * 4);
  prm.ukey     = (int*)take((size_t)N * 4);
  prm.akey     = (int*)take((size_t)N * 4);   // reused as plist
  prm.ainv_u   = (int*)take((size_t)N * 4);
  prm.nlist    = (int*)take((size_t)N * 4);
  prm.clist    = (int*)take((size_t)N * 4);
  prm.csum     = (float*)take((size_t)N * 128 * 4);
  prm.asum     = (float*)take((size_t)N * 128 * 4);
  prm.zbase  = (uint4*)ws;
  prm.zwords = (int)(zeroBytes / 16);

  int mb = 0;
  hipOccupancyMaxActiveBlocksPerMultiprocessor(&mb, (const void*)k_fused, 256, 0);
  if (mb < 1) mb = 1;
  int G = mb * 256;
  if (G > 1024) G = 1024;

  void* args[] = { (void*)&prm };
  hipLaunchCooperativeKernel((const void*)k_fused, dim3(G), dim3(256), args, 0, stream);
}

// Round 4
// 467.417 us; speedup vs baseline: 2.7481x; 2.7481x over previous
//
#include <hip/hip_runtime.h>

#define SCAN_BS 256
#define SCAN_IT 16
#define SCAN_CHUNK (SCAN_BS * SCAN_IT)   // 4096 words per chunk
#define NVOX 10000000
#define NAVOX 5000000
#define NWORDS1 312500                   // ceil(NVOX/32)
#define NWORDS2 156250                   // ceil(NAVOX/32)
#define VXYZK 1250000
#define BLK1 ((NWORDS1 + SCAN_CHUNK - 1) / SCAN_CHUNK)   // 77
#define BLK2 ((NWORDS2 + SCAN_CHUNK - 1) / SCAN_CHUNK)   // 39

__device__ __forceinline__ float leakyf(float x) { return x >= 0.0f ? x : 0.1f * x; }

// ctr: [0]=U uniq voxels, [1]=A assoc groups, [2]=K, [3]=flagged pts,
//      [4]=fg mode, [5]=mcount, [6]=ncount, [7]=cpts.  All-zero init is valid.
__device__ __forceinline__ int fg_get(const void* fgp, int i, int mode) {
  return mode ? (((const unsigned char*)fgp)[i] != 0) : (((const int*)fgp)[i] != 0);
}

__device__ __forceinline__ int rank_of(int key, const unsigned* bits,
                                       const unsigned* wordpfx, const unsigned* bsums) {
  int w = key >> 5, b = key & 31;
  return (int)(wordpfx[w] + bsums[w >> 12] + (unsigned)__popc(bits[w] & ((1u << b) - 1u)));
}

// voxelize + presence bits + fg dtype detect + passthrough copy out=pf (fused, independent work)
__global__ void k_vkey_copy(const float* __restrict__ pc, const int* __restrict__ bidx,
                            const unsigned* __restrict__ fgw, int nw,
                            int* __restrict__ vkey, unsigned* __restrict__ bits,
                            int* __restrict__ c, const float* __restrict__ pf,
                            float* __restrict__ out, int N) {
  int nth = gridDim.x * blockDim.x;
  int gtid = blockIdx.x * blockDim.x + threadIdx.x;
  for (int i = gtid; i < N; i += nth) {
    if (i < nw && fgw[i] > 1u) atomicOr(&c[4], 1);
    float x = pc[3 * i], y = pc[3 * i + 1], z = pc[3 * i + 2];
    int xi = (int)floorf((x - (-50.0f)) / 0.4f);
    int yi = (int)floorf((y - (-50.0f)) / 0.4f);
    int zi = (int)floorf((z - (-5.0f)) / 0.4f);
    xi = min(max(xi, 0), 249); yi = min(max(yi, 0), 249); zi = min(max(zi, 0), 19);
    int b = min(max(bidx[i], 0), 7);
    int key = ((b * 250 + xi) * 250 + yi) * 20 + zi;
    vkey[i] = key;
    atomicOr(&bits[key >> 5], 1u << (key & 31));
  }
  // passthrough copy, unroll-4 for MLP
  const float4* s4 = (const float4*)pf;
  float4* d4 = (float4*)out;
  int n4 = N * 32;
  int e = gtid;
  for (; e + 3 * nth < n4; e += 4 * nth) {
    float4 v0 = s4[e], v1 = s4[e + nth], v2 = s4[e + 2 * nth], v3 = s4[e + 3 * nth];
    d4[e] = v0; d4[e + nth] = v1; d4[e + 2 * nth] = v2; d4[e + 3 * nth] = v3;
  }
  for (; e < n4; e += nth) d4[e] = s4[e];
}

// popcount-scan over bit words: per-chunk exclusive word prefix + per-chunk sums.
__global__ void k_scan_pop(const unsigned* __restrict__ bits, int nwords,
                           unsigned* __restrict__ wordpfx, unsigned* __restrict__ bsums) {
  __shared__ unsigned s[SCAN_BS];
  int tid = threadIdx.x;
  long base = (long)blockIdx.x * SCAN_CHUNK + (long)tid * SCAN_IT;
  unsigned v[SCAN_IT];
  unsigned tsum = 0;
#pragma unroll
  for (int j = 0; j < SCAN_IT; ++j) {
    long idx = base + j;
    v[j] = (idx < (long)nwords) ? (unsigned)__popc(bits[idx]) : 0u;
    tsum += v[j];
  }
  unsigned x = tsum;
  s[tid] = x;
  for (int off = 1; off < SCAN_BS; off <<= 1) {
    __syncthreads();
    unsigned y = (tid >= off) ? s[tid - off] : 0u;
    __syncthreads();
    x += y;
    s[tid] = x;
  }
  if (tid == SCAN_BS - 1) bsums[blockIdx.x] = x;
  unsigned run = x - tsum;
#pragma unroll
  for (int j = 0; j < SCAN_IT; ++j) {
    long idx = base + j;
    if (idx < (long)nwords) { wordpfx[idx] = run; run += v[j]; }
  }
}

// exclusive-scan bsums (n <= 4096) in place; total -> *totalOut.
__global__ void k_scan_sums(unsigned* __restrict__ data, int n, int* __restrict__ totalOut) {
  __shared__ unsigned s[SCAN_BS];
  int tid = threadIdx.x;
  int base = tid * SCAN_IT;
  unsigned v[SCAN_IT];
  unsigned tsum = 0;
#pragma unroll
  for (int j = 0; j < SCAN_IT; ++j) {
    int idx = base + j;
    v[j] = (idx < n) ? data[idx] : 0u;
    tsum += v[j];
  }
  unsigned x = tsum;
  s[tid] = x;
  for (int off = 1; off < SCAN_BS; off <<= 1) {
    __syncthreads();
    unsigned y = (tid >= off) ? s[tid - off] : 0u;
    __syncthreads();
    x += y;
    s[tid] = x;
  }
  if (tid == SCAN_BS - 1) *totalOut = (int)x;
  unsigned run = x - tsum;
#pragma unroll
  for (int j = 0; j < SCAN_IT; ++j) {
    int idx = base + j;
    if (idx < n) { data[idx] = run; run += v[j]; }
  }
}

// inv + K + associate key/bits directly per point (akey[r] redundant same-value writes are benign)
__global__ void k_inv_akey(const int* __restrict__ vkey, const unsigned* __restrict__ bits,
                           const unsigned* __restrict__ wordpfx, const unsigned* __restrict__ bsums,
                           const void* __restrict__ fgp, int* __restrict__ inv,
                           int* __restrict__ akey, unsigned* __restrict__ abits,
                           int* __restrict__ c, int N) {
  int i = blockIdx.x * blockDim.x + threadIdx.x;
  bool valid = i < N;
  int mode = c[4];
  int r = 0;
  if (valid) {
    int k = vkey[i];
    r = rank_of(k, bits, wordpfx, bsums);
    inv[i] = r;
    int ak = (k / VXYZK / 2) * VXYZK + k % VXYZK;
    akey[r] = ak;
    atomicOr(&abits[ak >> 5], 1u << (ak & 31));
  }
  int fgr = (valid && fg_get(fgp, i, mode)) ? r : -1;
  for (int off = 32; off > 0; off >>= 1) fgr = max(fgr, __shfl_down(fgr, off));
  if ((threadIdx.x & 63) == 0 && fgr >= 0) atomicMax(&c[2], fgr + 1);
}

// ainv + group member count fused.
__global__ void k_ainv(const int* __restrict__ akey, const unsigned* __restrict__ abits,
                       const unsigned* __restrict__ awordpfx, const unsigned* __restrict__ bsums,
                       int* __restrict__ ainv, unsigned* __restrict__ gcnt,
                       const int* __restrict__ c, int N) {
  int r = blockIdx.x * blockDim.x + threadIdx.x;
  if (r >= N || r >= c[0]) return;
  int g = rank_of(akey[r], abits, awordpfx, bsums);
  ainv[r] = g;
  atomicAdd(&gcnt[g], 1u);
}

// mlist: clusters in multi-member groups; nlist: valid subset (r < K).
__global__ void k_build_lists(const int* __restrict__ ainv_u, const unsigned* __restrict__ gcnt,
                              int* __restrict__ mlist, int* __restrict__ nlist,
                              unsigned char* __restrict__ needp, int* __restrict__ c, int N) {
  int r = blockIdx.x * blockDim.x + threadIdx.x;
  if (r >= N || r >= c[0]) return;
  if (gcnt[ainv_u[r]] >= 2u) {
    int mp = atomicAdd(&c[5], 1);
    mlist[mp] = r;
    if (r < c[2]) {
      needp[r] = 1;
      int np = atomicAdd(&c[6], 1);
      nlist[np] = r;
    }
  }
}

// Fused: (A) zero only needed csum/asum rows; (B) filter contributing fg points.
__global__ void k_zero_filter(const int* __restrict__ mlist, const int* __restrict__ ainv_u,
                              const void* __restrict__ fgp, const int* __restrict__ inv,
                              const unsigned char* __restrict__ needp,
                              float* __restrict__ csum, float* __restrict__ asum,
                              float* __restrict__ cnt, int* __restrict__ clist,
                              int* __restrict__ c, int N) {
  int stride = gridDim.x * blockDim.x;
  int tid0 = blockIdx.x * blockDim.x + threadIdx.x;
  int K = c[2];
  int totalA = c[5] * 128;
  for (int idx = tid0; idx < totalA; idx += stride) {
    int r = mlist[idx >> 7];
    int d = idx & 127;
    asum[(size_t)ainv_u[r] * 128 + d] = 0.0f;
    if (r < K) csum[(size_t)r * 128 + d] = 0.0f;
  }
  int mode = c[4];
  for (int i = tid0; i < N; i += stride) {
    if (!fg_get(fgp, i, mode)) continue;
    int r = inv[i];
    if (!needp[r]) continue;
    atomicAdd(&cnt[r], 1.0f);
    int p = atomicAdd(&c[7], 1);
    clist[p] = i;
  }
}

__global__ void k_csum_accum(const float* __restrict__ pf, const int* __restrict__ clist,
                             const int* __restrict__ inv, float* __restrict__ csum,
                             const int* __restrict__ c) {
  int total = c[7] * 128;
  int stride = gridDim.x * blockDim.x;
  for (int idx = blockIdx.x * blockDim.x + threadIdx.x; idx < total; idx += stride) {
    int i = clist[idx >> 7];
    int d = idx & 127;
    atomicAdd(&csum[(size_t)inv[i] * 128 + d], pf[(size_t)i * 128 + d]);
  }
}

// In-place projection of needed clusters + fused asum/acnt accumulation.
__global__ __launch_bounds__(128) void k_proj_asum(
    float* __restrict__ cs, const float* __restrict__ cnt, const int* __restrict__ nlist,
    const int* __restrict__ ainv_u, float* __restrict__ asum, float* __restrict__ acnt,
    const float* __restrict__ W, const float* __restrict__ bb,
    const float* __restrict__ gg, const float* __restrict__ be,
    const float* __restrict__ mm, const float* __restrict__ vv, const int* __restrict__ c) {
  int nc = c[6];
  int ntiles = (nc + 15) >> 4;
  __shared__ __align__(16) float tile[16][128];
  __shared__ int srow[16];
  int d = threadIdx.x;
  for (int tb = blockIdx.x; tb < ntiles; tb += gridDim.x) {
    int base = tb * 16;
    if (d < 16) srow[d] = (base + d < nc) ? nlist[base + d] : -1;
    __syncthreads();
    for (int p = 0; p < 16; ++p) {
      int r = srow[p];
      tile[p][d] = (r >= 0) ? cs[(size_t)r * 128 + d] / fmaxf(cnt[r], 1.0f) : 0.0f;
    }
    __syncthreads();
    float acc[16];
#pragma unroll
    for (int p = 0; p < 16; ++p) acc[p] = 0.0f;
    for (int k4 = 0; k4 < 32; ++k4) {
      float w0 = W[(4 * k4 + 0) * 128 + d];
      float w1 = W[(4 * k4 + 1) * 128 + d];
      float w2 = W[(4 * k4 + 2) * 128 + d];
      float w3 = W[(4 * k4 + 3) * 128 + d];
#pragma unroll
      for (int p = 0; p < 16; ++p) {
        float4 t4 = *(const float4*)&tile[p][4 * k4];
        acc[p] = fmaf(t4.x, w0, acc[p]);
        acc[p] = fmaf(t4.y, w1, acc[p]);
        acc[p] = fmaf(t4.z, w2, acc[p]);
        acc[p] = fmaf(t4.w, w3, acc[p]);
      }
    }
    float biasd = bb[d], scale = gg[d] / sqrtf(vv[d] + 1e-5f), md = mm[d], bed = be[d];
    for (int p = 0; p < 16; ++p) {
      int r = srow[p];
      if (r >= 0) {
        float pre = acc[p] + biasd;
        float val = leakyf((pre - md) * scale + bed);
        cs[(size_t)r * 128 + d] = val;
        int g = ainv_u[r];
        atomicAdd(&asum[(size_t)g * 128 + d], val);
        if (d == 0) atomicAdd(&acnt[g], 1.0f);
      }
    }
    __syncthreads();
  }
}

// flag for multi-group clusters; per-element diff FIRST (bit-exact singleton cancellation).
__global__ void k_amask2(const float* __restrict__ cs, const float* __restrict__ asum,
                         const float* __restrict__ acnt, const int* __restrict__ ainv_u,
                         const int* __restrict__ mlist, const int* __restrict__ c,
                         unsigned* __restrict__ flag) {
  int mcount = c[5];
  int groups = gridDim.x * (blockDim.x >> 6);
  int j0 = blockIdx.x * (blockDim.x >> 6) + (threadIdx.x >> 6);
  int lane = threadIdx.x & 63;
  int K = c[2];
  for (int j = j0; j < mcount; j += groups) {
    int r = mlist[j];
    int g = ainv_u[r];
    float mc = fmaxf(acnt[g], 1.0f);
    bool valid = r < K;
    size_t rb = (size_t)r * 128, gb = (size_t)g * 128;
    float c0 = valid ? cs[rb + lane] : 0.0f;
    float c1 = valid ? cs[rb + 64 + lane] : 0.0f;
    float s = (c0 - asum[gb + lane] / mc) + (c1 - asum[gb + 64 + lane] / mc);
    for (int off = 32; off > 0; off >>= 1) s += __shfl_down(s, off);
    if (lane == 0) flag[r] = (s > 0.0f) ? 1u : 0u;
  }
}

// Flagged-point list with wave-aggregated atomic (one atomicAdd per wave).
__global__ void k_plist(const int* __restrict__ inv, const unsigned* __restrict__ flag,
                        int* __restrict__ plist, int* __restrict__ c, int N) {
  int i = blockIdx.x * blockDim.x + threadIdx.x;
  bool pred = (i < N) && (flag[inv[i]] != 0u);
  unsigned long long m = __ballot(pred);
  int lane = threadIdx.x & 63;
  int cnt = __popcll(m);
  int base = 0;
  if (lane == 0 && cnt) base = atomicAdd(&c[3], cnt);
  base = __shfl(base, 0);
  if (pred) plist[base + __popcll(m & ((1ull << lane) - 1ull))] = i;
}

// Final GEMM only for flagged points.
__global__ __launch_bounds__(128) void k_fgemm(
    const float* __restrict__ pf, const float* __restrict__ cs,
    const float* __restrict__ asum, const float* __restrict__ acnt,
    const int* __restrict__ inv, const int* __restrict__ ainv_u,
    const int* __restrict__ plist, const int* __restrict__ c,
    const float* __restrict__ W, const float* __restrict__ bb,
    const float* __restrict__ gg, const float* __restrict__ be,
    const float* __restrict__ mm, const float* __restrict__ vv,
    float* __restrict__ out) {
  int pcnt = c[3];
  if (pcnt <= 1) return;  // gate: amask.sum() <= 1 -> pure passthrough
  int K = c[2];
  int ntiles = (pcnt + 15) >> 4;
  __shared__ __align__(16) float tile[16][384];
  __shared__ int si[16], sr[16], sg[16];
  __shared__ float smc[16];
  int t = threadIdx.x;
  for (int tb = blockIdx.x; tb < ntiles; tb += gridDim.x) {
    int base = tb * 16;
    if (t < 16) {
      int i = (base + t < pcnt) ? plist[base + t] : -1;
      si[t] = i;
      int r = (i >= 0) ? inv[i] : 0;
      sr[t] = r;
      int g = ainv_u[r];
      sg[t] = g;
      smc[t] = fmaxf(acnt[g], 1.0f);
    }
    __syncthreads();
    for (int e = t; e < 16 * 96; e += 128) {
      int p = e / 96, f4 = e % 96;
      int i = si[p];
      float4 v = make_float4(0.f, 0.f, 0.f, 0.f);
      if (i >= 0) {
        if (f4 < 32) {
          v = ((const float4*)pf)[(size_t)i * 32 + f4];
        } else if (f4 < 64) {
          int r = sr[p];
          if (r < K) v = ((const float4*)cs)[(size_t)r * 32 + (f4 - 32)];
        } else {
          float4 a = ((const float4*)asum)[(size_t)sg[p] * 32 + (f4 - 64)];
          float mc = smc[p];
          v = make_float4(a.x / mc, a.y / mc, a.z / mc, a.w / mc);
        }
      }
      *(float4*)&tile[p][f4 * 4] = v;
    }
    __syncthreads();
    float acc[16];
#pragma unroll
    for (int p = 0; p < 16; ++p) acc[p] = 0.0f;
    for (int k4 = 0; k4 < 96; ++k4) {
      float w0 = W[(4 * k4 + 0) * 128 + t];
      float w1 = W[(4 * k4 + 1) * 128 + t];
      float w2 = W[(4 * k4 + 2) * 128 + t];
      float w3 = W[(4 * k4 + 3) * 128 + t];
#pragma unroll
      for (int p = 0; p < 16; ++p) {
        float4 t4 = *(const float4*)&tile[p][4 * k4];
        acc[p] = fmaf(t4.x, w0, acc[p]);
        acc[p] = fmaf(t4.y, w1, acc[p]);
        acc[p] = fmaf(t4.z, w2, acc[p]);
        acc[p] = fmaf(t4.w, w3, acc[p]);
      }
    }
    float biasd = bb[t], scale = gg[t] / sqrtf(vv[t] + 1e-5f), md = mm[t], bed = be[t];
    for (int p = 0; p < 16; ++p) {
      int i = si[p];
      if (i >= 0) {
        float pre = acc[p] + biasd;
        out[(size_t)i * 128 + t] = leakyf((pre - md) * scale + bed);
      }
    }
    __syncthreads();
  }
}

extern "C" void kernel_launch(void* const* d_in, const int* in_sizes, int n_in,
                              void* d_out, int out_size, void* d_ws, size_t ws_size,
                              hipStream_t stream) {
  (void)n_in; (void)out_size; (void)ws_size;
  const float* pf   = (const float*)d_in[0];
  const float* pc   = (const float*)d_in[1];
  const int*   bidx = (const int*)d_in[2];
  const void*  fgp  = d_in[3];
  const float* Wpf  = (const float*)d_in[5];
  const float* bpf  = (const float*)d_in[6];
  const float* gpf  = (const float*)d_in[7];
  const float* bepf = (const float*)d_in[8];
  const float* mpf  = (const float*)d_in[9];
  const float* vpf  = (const float*)d_in[10];
  const float* Wcp  = (const float*)d_in[11];
  const float* bcp  = (const float*)d_in[12];
  const float* gcp  = (const float*)d_in[13];
  const float* becp = (const float*)d_in[14];
  const float* mcp  = (const float*)d_in[15];
  const float* vcp  = (const float*)d_in[16];
  float* out = (float*)d_out;
  int N = in_sizes[0] / 128;

  char* ws = (char*)d_ws;
  size_t o = 0;
  auto take = [&](size_t bytes) -> void* {
    void* p = ws + o;
    o += (bytes + 255) & ~(size_t)255;
    return p;
  };
  // ---- zeroed region (ONE memset) ----
  unsigned* bits   = (unsigned*)take((size_t)NWORDS1 * 4);
  unsigned* abits  = (unsigned*)take((size_t)NWORDS2 * 4);
  float* cnt       = (float*)take((size_t)N * 4);
  float* acnt      = (float*)take((size_t)N * 4);
  unsigned* flag   = (unsigned*)take((size_t)N * 4);
  unsigned* gcnt   = (unsigned*)take((size_t)N * 4);
  unsigned char* needp = (unsigned char*)take((size_t)N);
  int* ctr         = (int*)take(256);
  size_t zeroBytes = o;
  // ---- scratch (no init needed) ----
  unsigned* wordpfx  = (unsigned*)take((size_t)NWORDS1 * 4);
  unsigned* awordpfx = (unsigned*)take((size_t)NWORDS2 * 4);
  unsigned* bsums1 = (unsigned*)take((size_t)4096 * 4);
  unsigned* bsums2 = (unsigned*)take((size_t)4096 * 4);
  int* vkey        = (int*)take((size_t)N * 4);   // reused as mlist after inv built
  int* inv         = (int*)take((size_t)N * 4);
  int* akey        = (int*)take((size_t)N * 4);   // reused as plist after ainv built
  int* ainv_u      = (int*)take((size_t)N * 4);
  int* nlist       = (int*)take((size_t)N * 4);
  int* clist       = (int*)take((size_t)N * 4);
  float* csum      = (float*)take((size_t)N * 128 * 4);  // becomes cfa in place
  float* asum      = (float*)take((size_t)N * 128 * 4);
  int* mlist = vkey;
  int* plist = akey;

  hipMemsetAsync(ws, 0, zeroBytes, stream);

  int nb = (N + 255) / 256;
  int nw = N / 4;
  // fused voxelize + passthrough copy
  k_vkey_copy<<<2048, 256, 0, stream>>>(pc, bidx, (const unsigned*)fgp, nw, vkey, bits,
                                        ctr, pf, out, N);

  k_scan_pop<<<BLK1, SCAN_BS, 0, stream>>>(bits, NWORDS1, wordpfx, bsums1);
  k_scan_sums<<<1, SCAN_BS, 0, stream>>>(bsums1, BLK1, &ctr[0]);
  k_inv_akey<<<nb, 256, 0, stream>>>(vkey, bits, wordpfx, bsums1, fgp, inv,
                                     akey, abits, ctr, N);

  k_scan_pop<<<BLK2, SCAN_BS, 0, stream>>>(abits, NWORDS2, awordpfx, bsums2);
  k_scan_sums<<<1, SCAN_BS, 0, stream>>>(bsums2, BLK2, &ctr[1]);
  k_ainv<<<nb, 256, 0, stream>>>(akey, abits, awordpfx, bsums2, ainv_u, gcnt, ctr, N);

  k_build_lists<<<nb, 256, 0, stream>>>(ainv_u, gcnt, mlist, nlist, needp, ctr, N);
  k_zero_filter<<<1024, 256, 0, stream>>>(mlist, ainv_u, fgp, inv, needp,
                                          csum, asum, cnt, clist, ctr, N);
  k_csum_accum<<<1024, 256, 0, stream>>>(pf, clist, inv, csum, ctr);
  k_proj_asum<<<512, 128, 0, stream>>>(csum, cnt, nlist, ainv_u, asum, acnt,
                                       Wcp, bcp, gcp, becp, mcp, vcp, ctr);
  k_amask2<<<512, 256, 0, stream>>>(csum, asum, acnt, ainv_u, mlist, ctr, flag);

  k_plist<<<nb, 256, 0, stream>>>(inv, flag, plist, ctr, N);
  k_fgemm<<<1024, 128, 0, stream>>>(pf, csum, asum, acnt, inv, ainv_u, plist, ctr,
                                    Wpf, bpf, gpf, bepf, mpf, vpf, out);
}